// Round 6
// baseline (351.839 us; speedup 1.0000x reference)
//
#include <hip/hip_runtime.h>

#define NPTS 8192
#define NBATCH 4
#define NTOT (NBATCH * NPTS)     // 32768
#define NN 16
#define RAD2 0.25f
#define EPSF 1e-4f
#define BIGF 1e30f

// ---- grid: cell 0.5 over [-4,4), 16 cells/dim, NO ghosts; x fastest, then y, z, batch ----
#define GC 16
#define CBS (GC * GC * GC)        // 4096 cells per batch
#define NCELL_TOT (NBATCH * CBS)  // 16384

// ---- search: block = one (b,cz,cy) row; wave = 64 consecutive sorted points ----
#define STHR 512
#define SNW 8
#define SNB (NBATCH * GC * GC)    // 1024 row-blocks
#define QS 17                     // queue stride (bank-safe)
#define QTRIG 13                  // drain trigger; cap 16, <=4 pushes between checks

// ---- ws layout (bytes) ----
#define WS_COUNTS 0
#define WS_RANGES (WS_COUNTS + NCELL_TOT * 4)
#define WS_CURSOR (WS_RANGES + NCELL_TOT * 8)
#define WS_SORTED (WS_CURSOR + NCELL_TOT * 4)          // float4 (NTOT+64 padded)
#define WS_BSUMS  (WS_SORTED + (NTOT + 64) * 16)
#define WS_NEEDED (WS_BSUMS + SNB * 4)                 // ~790 KB

__device__ __forceinline__ int cellc(float v) {
  return min(max((int)floorf((v + 4.0f) * 2.0f), 0), GC - 1);
}

// refined rsqrt: v_rsq + one Newton step (~1-2 ulp; mean over 512K terms absorbs it)
__device__ __forceinline__ float prsqrt(float x) {
  float r = __builtin_amdgcn_rsqf(x);
  r = r * fmaf(-0.5f * x * r, r, 1.5f);
  return r;
}

__device__ __forceinline__ void insert16(float (&td)[NN], float& thrmax, float v) {
  if (v < thrmax) {
    bool done = false;
#pragma unroll
    for (int k = 0; k < NN; ++k) {
      const bool hit = (!done) && (td[k] == thrmax);
      if (hit) td[k] = v;
      done = done || hit;
    }
    thrmax = td[0];
#pragma unroll
    for (int k = 1; k < NN; ++k) thrmax = fmaxf(thrmax, td[k]);
  }
}

__device__ __forceinline__ void drain_queue(float* hq, int qb, int& cnt,
                                            float (&td)[NN], float& thrmax) {
#pragma unroll
  for (int c = 0; c < 16; ++c) {
    const float v = (c < cnt) ? hq[qb + c] : BIGF;
    insert16(td, thrmax, v);
  }
  cnt = 0;
}

// ============ build ============

__global__ __launch_bounds__(256)
void zero_kernel(int* __restrict__ counts) {
  const int i = blockIdx.x * 256 + threadIdx.x;
  if (i < NCELL_TOT) counts[i] = 0;
}

__global__ __launch_bounds__(256)
void hist_kernel(const float* __restrict__ pts, int* __restrict__ counts) {
  const int i = blockIdx.x * 256 + threadIdx.x;
  if (i >= NTOT) return;
  const int b = i >> 13;
  const float x = pts[i * 3 + 0], y = pts[i * 3 + 1], z = pts[i * 3 + 2];
  const int c = ((b * GC + cellc(z)) * GC + cellc(y)) * GC + cellc(x);
  atomicAdd(&counts[c], 1);
}

__global__ __launch_bounds__(1024)
void scan_kernel(const int* __restrict__ counts, int2* __restrict__ ranges,
                 int* __restrict__ cursor) {
  __shared__ int wsum[16];
  __shared__ int woff[16];
  __shared__ int stot;
  const int b = blockIdx.x;
  const int tid = threadIdx.x;
  const int wid = tid >> 6;
  const int lane = tid & 63;
  const int g0 = b * CBS;
  int running = b * NPTS;
  for (int chunk = 0; chunk < CBS; chunk += 1024) {
    const int idx = chunk + tid;
    const int v = counts[g0 + idx];
    int x = v;
    for (int off = 1; off < 64; off <<= 1) {
      const int t = __shfl_up(x, off, 64);
      if (lane >= off) x += t;
    }
    if (lane == 63) wsum[wid] = x;
    __syncthreads();
    if (wid == 0) {
      int s = (lane < 16) ? wsum[lane] : 0;
      for (int off = 1; off < 16; off <<= 1) {
        const int t = __shfl_up(s, off, 64);
        if (lane >= off) s += t;
      }
      if (lane < 16) woff[lane] = s - wsum[lane];
      if (lane == 15) stot = s;
    }
    __syncthreads();
    const int excl = running + woff[wid] + x - v;
    ranges[g0 + idx] = make_int2(excl, v);
    cursor[g0 + idx] = excl;
    running += stot;
    __syncthreads();
  }
}

__global__ __launch_bounds__(256)
void scatter_kernel(const float* __restrict__ pts, int* __restrict__ cursor,
                    float4* __restrict__ sorted) {
  const int i = blockIdx.x * 256 + threadIdx.x;
  if (i >= NTOT) return;
  const int b = i >> 13;
  const float x = pts[i * 3 + 0], y = pts[i * 3 + 1], z = pts[i * 3 + 2];
  const int c = ((b * GC + cellc(z)) * GC + cellc(y)) * GC + cellc(x);
  const int pos = atomicAdd(&cursor[c], 1);
  sorted[pos] = make_float4(x, y, z, 0.0f);
}

// ============ search ============

#define PROC(KK) {                                                              \
    const float bx = __int_as_float(__builtin_amdgcn_readlane(__float_as_int(q.x), (KK))); \
    const float by = __int_as_float(__builtin_amdgcn_readlane(__float_as_int(q.y), (KK))); \
    const float bz = __int_as_float(__builtin_amdgcn_readlane(__float_as_int(q.z), (KK))); \
    const float ddx = bx - xi, ddy = by - yi, ddz = bz - zi;                    \
    const float d2 = fmaf(ddx, ddx, fmaf(ddy, ddy, ddz * ddz));                 \
    if (d2 < lim && d2 != 0.0f) { hq[qb + cnt] = d2; ++cnt; }                   \
  }

#define DRAINSTEP {                                                             \
    drain_queue(hq, qb, cnt, td, thrmax);                                       \
    nodrain = false;                                                            \
    lim = fminf(thrmax, RAD2);                                                  \
  }

__global__ __launch_bounds__(STHR)
void search_kernel(const float4* __restrict__ sorted, const int2* __restrict__ rngs,
                   float* __restrict__ bsums) {
  __shared__ float hq[STHR * QS];     // 34.8 KiB per-thread queues
  __shared__ float wloss[SNW];

  const int tid = threadIdx.x;
  const int wv = tid >> 6;
  const int lane = tid & 63;
  const int bid = blockIdx.x;
  const int bb = bid >> 8;
  const int cz = (bid >> 4) & 15;
  const int cy = bid & 15;

  // this row's point range (cells bid*16 .. bid*16+15 are contiguous)
  const int2 r0 = rngs[bid * GC];
  const int2 r15 = rngs[bid * GC + GC - 1];
  const int row_start = r0.x;
  const int row_end = r15.x + r15.y;
  const int nrow = row_end - row_start;

  const int qb = tid * QS;
  float wacc = 0.0f;

  for (int g = wv; g * 64 < nrow; g += SNW) {
    const int gstart = row_start + g * 64;
    const int lastv = min(63, row_end - gstart - 1);   // uniform
    const float4 pt = sorted[gstart + lane];           // pad covers tail overrun
    const bool pv = (lane <= lastv);
    const float xi = pv ? pt.x : 1e18f;
    const float yi = pv ? pt.y : 1e18f;
    const float zi = pv ? pt.z : 1e18f;
    const int cxl = cellc(xi);
    // points sorted by cx within row: min = lane0, max = last valid lane
    const int cxmin = __builtin_amdgcn_readfirstlane(cxl);
    const int cxmax = __builtin_amdgcn_readlane(cxl, lastv);
    const int xlo = max(cxmin - 1, 0);
    const int xhi = min(cxmax + 1, GC - 1);

    float td[NN];
#pragma unroll
    for (int k = 0; k < NN; ++k) td[k] = BIGF;
    float thrmax = BIGF;
    float lim = RAD2;
    int cnt = 0;
    bool nodrain = true;

    for (int dz = -1; dz <= 1; ++dz) {
      const int czn = cz + dz;
      if (czn < 0 || czn >= GC) continue;
      for (int dy = -1; dy <= 1; ++dy) {
        const int cyn = cy + dy;
        if (cyn < 0 || cyn >= GC) continue;
        const int cb = ((bb * GC + czn) * GC + cyn) * GC;
        const int2 ra = rngs[cb + xlo];
        const int2 rb = rngs[cb + xhi];
        int j = ra.x;
        const int e = rb.x + rb.y;
        if (j >= e) continue;
        float4 q = sorted[j + lane];                   // coalesced chunk load
        while (j < e) {
          const int rem = e - j;
          float4 qn = q;
          if (rem > 64) qn = sorted[j + 64 + lane];    // register prefetch
          if (rem >= 64) {
            for (int k0 = 0; k0 < 64; k0 += 4) {
              PROC(k0) PROC(k0 + 1) PROC(k0 + 2) PROC(k0 + 3)
              if (__any(cnt >= QTRIG)) DRAINSTEP
            }
          } else {
            for (int k0 = 0; k0 < rem; ++k0) {
              PROC(k0)
              if ((k0 & 3) == 3 && __any(cnt >= QTRIG)) DRAINSTEP
            }
            if (__any(cnt >= QTRIG)) DRAINSTEP
          }
          q = qn;
          j += 64;
        }
      }
    }

    float loss = 0.0f;
    if (nodrain) {
      // no lane exceeded 16 hits: queue holds the complete hit set (all < RAD2)
      int cm = cnt;
      cm = max(cm, __shfl_xor(cm, 1));
      cm = max(cm, __shfl_xor(cm, 2));
      cm = max(cm, __shfl_xor(cm, 4));
      cm = max(cm, __shfl_xor(cm, 8));
      cm = max(cm, __shfl_xor(cm, 16));
      cm = max(cm, __shfl_xor(cm, 32));
      for (int c = 0; c < cm; ++c) {
        if (c < cnt) loss += prsqrt(hq[qb + c] + EPSF);
      }
    } else {
      drain_queue(hq, qb, cnt, td, thrmax);
#pragma unroll
      for (int k = 0; k < NN; ++k) {
        if (td[k] < RAD2) loss += prsqrt(td[k] + EPSF);
      }
    }
    loss += __shfl_xor(loss, 1);
    loss += __shfl_xor(loss, 2);
    loss += __shfl_xor(loss, 4);
    loss += __shfl_xor(loss, 8);
    loss += __shfl_xor(loss, 16);
    loss += __shfl_xor(loss, 32);
    wacc += loss;
  }

  if (lane == 0) wloss[wv] = wacc;
  __syncthreads();
  if (tid == 0) {
    float s = 0.0f;
#pragma unroll
    for (int w = 0; w < SNW; ++w) s += wloss[w];
    bsums[bid] = s;
  }
}

__global__ __launch_bounds__(256)
void finalize_kernel(const float* __restrict__ block_sums, int nblocks,
                     float* __restrict__ out) {
  __shared__ float s[256];
  float v = 0.0f;
  for (int idx = threadIdx.x; idx < nblocks; idx += 256) v += block_sums[idx];
  s[threadIdx.x] = v;
  __syncthreads();
  for (int off = 128; off > 0; off >>= 1) {
    if (threadIdx.x < off) s[threadIdx.x] += s[threadIdx.x + off];
    __syncthreads();
  }
  if (threadIdx.x == 0) out[0] = s[0] / (float)(NBATCH * NPTS * NN);
}

// ============ dense fallback (if ws too small) ============

#define DTILE 1024
#define DNT 512
#define DNW 8
#define DNB (NTOT / 64)
#define CSTRIDE 17

__global__ __launch_bounds__(DNT)
void dense_kernel(const float* __restrict__ pts, float* __restrict__ block_sums) {
  __shared__ float4 tile[DTILE];
  __shared__ float buf[DNT * CSTRIDE];

  const int tid = threadIdx.x;
  const int wave = tid >> 6;
  const int lane = tid & 63;
  const int bid = blockIdx.x;
  const int b = bid / (NPTS / 64);
  const int base = (bid % (NPTS / 64)) * 64;
  const float* __restrict__ bp = pts + (size_t)b * NPTS * 3;

  const int i = base + lane;
  const float xi = bp[i * 3 + 0];
  const float yi = bp[i * 3 + 1];
  const float zi = bp[i * 3 + 2];

  float td[NN];
#pragma unroll
  for (int k = 0; k < NN; ++k) td[k] = BIGF;
  float thrmax = BIGF;
  int cnt = 0;
  const int qbase = tid * CSTRIDE;

  for (int tb = 0; tb < NPTS; tb += DTILE) {
    for (int pp = tid; pp < DTILE; pp += DNT) {
      const float* sp = bp + (size_t)(tb + pp) * 3;
      tile[pp] = make_float4(sp[0], sp[1], sp[2], 0.0f);
    }
    __syncthreads();
    const int jb = wave * (DTILE / DNW);
    for (int jj = 0; jj < DTILE / DNW; ++jj) {
      const float4 q = tile[jb + jj];
      const float ddx = q.x - xi, ddy = q.y - yi, ddz = q.z - zi;
      const float d2 = fmaf(ddx, ddx, fmaf(ddy, ddy, ddz * ddz));
      if (d2 < RAD2 && d2 != 0.0f) {
        buf[qbase + cnt] = d2;
        ++cnt;
      }
      if (__any(cnt >= QTRIG)) drain_queue(buf, qbase, cnt, td, thrmax);
    }
    __syncthreads();
  }
  drain_queue(buf, qbase, cnt, td, thrmax);
#pragma unroll
  for (int k = 0; k < NN; ++k) buf[qbase + k] = td[k];
  __syncthreads();

  if (wave == 0) {
    float sd[NN];
#pragma unroll
    for (int k = 0; k < NN; ++k) sd[k] = BIGF;
    float smax = BIGF;
    for (int w = 0; w < DNW; ++w) {
      for (int c = 0; c < NN; ++c) {
        insert16(sd, smax, buf[(w * 64 + lane) * CSTRIDE + c]);
      }
    }
    float loss = 0.0f;
#pragma unroll
    for (int k = 0; k < NN; ++k) {
      if (sd[k] < RAD2) loss += 1.0f / sqrtf(sd[k] + EPSF);
    }
    for (int off = 32; off > 0; off >>= 1) loss += __shfl_down(loss, off);
    if (lane == 0) block_sums[bid] = loss;
  }
}

// ============ launch ============

extern "C" void kernel_launch(void* const* d_in, const int* in_sizes, int n_in,
                              void* d_out, int out_size, void* d_ws, size_t ws_size,
                              hipStream_t stream) {
  const float* pts = (const float*)d_in[0];
  float* out = (float*)d_out;
  char* ws = (char*)d_ws;

  if (ws_size >= (size_t)WS_NEEDED) {
    int* counts = (int*)(ws + WS_COUNTS);
    int2* rngs = (int2*)(ws + WS_RANGES);
    int* cursor = (int*)(ws + WS_CURSOR);
    float4* sorted = (float4*)(ws + WS_SORTED);
    float* bsums = (float*)(ws + WS_BSUMS);

    zero_kernel<<<(NCELL_TOT + 255) / 256, 256, 0, stream>>>(counts);
    hist_kernel<<<(NTOT + 255) / 256, 256, 0, stream>>>(pts, counts);
    scan_kernel<<<NBATCH, 1024, 0, stream>>>(counts, rngs, cursor);
    scatter_kernel<<<(NTOT + 255) / 256, 256, 0, stream>>>(pts, cursor, sorted);
    search_kernel<<<SNB, STHR, 0, stream>>>(sorted, rngs, bsums);
    finalize_kernel<<<1, 256, 0, stream>>>(bsums, SNB, out);
  } else {
    float* bsums = (float*)ws;
    dense_kernel<<<DNB, DNT, 0, stream>>>(pts, bsums);
    finalize_kernel<<<1, 256, 0, stream>>>(bsums, DNB, out);
  }
}

// Round 8
// 115.262 us; speedup vs baseline: 3.0525x; 3.0525x over previous
//
#include <hip/hip_runtime.h>

#define NPTS 8192
#define NBATCH 4
#define NTOT (NBATCH * NPTS)     // 32768
#define NN 16
#define RAD2 0.25f
#define EPSF 1e-4f
#define BIGF 1e30f

// ---- grid: cell 0.5 over [-4,4), 16 cells/dim; x fastest, then y, z, batch ----
#define GC 16
#define CBS (GC * GC * GC)        // 4096 cells per batch
#define NCELL_TOT (NBATCH * CBS)  // 16384

// ---- fused build: 64 blocks x 256 (co-resident on 256 CUs; spin barriers) ----
#define BLD_NB 64
#define BLD_NT 256

// ---- search: one wave per point. TRUE hit stats (N(0,1)^3, r=0.5):
// mean ~96 hits/point, central points ~270-330. HCAP=384 covers max (+8 sigma).
#define STHR 256
#define SWV 4
#define SNB (NTOT / SWV)          // 8192 blocks
#define HCAP 384

// ---- ws layout (bytes) ----
#define WS_COUNTS 0
#define WS_RANGES (WS_COUNTS + NCELL_TOT * 4)          // int2
#define WS_CURSOR (WS_RANGES + NCELL_TOT * 8)
#define WS_SORTED (WS_CURSOR + NCELL_TOT * 4)          // float4 (+64 pad)
#define WS_BSUMS  (WS_SORTED + (NTOT + 64) * 16)
#define WS_BS2    (WS_BSUMS + SNB * 4)                 // per-block scan sums
#define WS_BAR    (WS_BS2 + BLD_NB * 4)                // 4 barrier counters
#define WS_NEEDED (WS_BAR + 16)                        // ~801 KB

__device__ __forceinline__ int cellc(float v) {
  return min(max((int)floorf((v + 4.0f) * 2.0f), 0), GC - 1);
}

// refined rsqrt: v_rsq + one Newton step (~1-2 ulp; mean over 512K terms absorbs it)
__device__ __forceinline__ float prsqrt(float x) {
  float r = __builtin_amdgcn_rsqf(x);
  r = r * fmaf(-0.5f * x * r, r, 1.5f);
  return r;
}

#define CE(a, b) { const float lo_ = fminf(a, b); const float hi_ = fmaxf(a, b); a = lo_; b = hi_; }

// ============ fused build (zero -> hist -> scan -> scatter, spin barriers) ============

__device__ __forceinline__ void gbar(int* bar, int idx) {
  __threadfence();           // agent-scope release of prior writes
  __syncthreads();
  if (threadIdx.x == 0) {
    __hip_atomic_fetch_add(&bar[idx], 1, __ATOMIC_ACQ_REL, __HIP_MEMORY_SCOPE_AGENT);
    while (__hip_atomic_load(&bar[idx], __ATOMIC_ACQUIRE, __HIP_MEMORY_SCOPE_AGENT) < BLD_NB)
      __builtin_amdgcn_s_sleep(4);
  }
  __syncthreads();
  // all subsequent cross-block reads use agent-scope atomics (L1-stale safe)
}

__global__ __launch_bounds__(BLD_NT, 1)
void build_kernel(const float* __restrict__ pts, int* __restrict__ counts,
                  int2* __restrict__ ranges, int* __restrict__ cursor,
                  float4* __restrict__ sorted, int* __restrict__ bs2,
                  int* __restrict__ bar) {
  const int tid = threadIdx.x;
  const int bidx = blockIdx.x;
  const int lane = tid & 63;
  const int wid = tid >> 6;
  __shared__ int wpre[4];
  __shared__ int wtot;

  // P0: zero own 256 cells (64*256 == 16384 cells exactly)
  counts[bidx * 256 + tid] = 0;
  gbar(bar, 0);

  // P1: histogram (device-scope atomics)
  for (int i = bidx * BLD_NT + tid; i < NTOT; i += BLD_NB * BLD_NT) {
    const int b = i >> 13;
    const float x = pts[i * 3 + 0], y = pts[i * 3 + 1], z = pts[i * 3 + 2];
    const int c = ((b * GC + cellc(z)) * GC + cellc(y)) * GC + cellc(x);
    atomicAdd(&counts[c], 1);
  }
  gbar(bar, 1);

  // P2a: block-local scan of own 256 cells
  const int g = bidx * 256 + tid;
  const int v = __hip_atomic_load(&counts[g], __ATOMIC_RELAXED, __HIP_MEMORY_SCOPE_AGENT);
  int x = v;
  for (int off = 1; off < 64; off <<= 1) {
    const int t = __shfl_up(x, off, 64);
    if (lane >= off) x += t;
  }
  if (lane == 63) wpre[wid] = x;
  __syncthreads();
  if (tid == 0) {
    int a = 0;
#pragma unroll
    for (int w = 0; w < 4; ++w) { const int t = wpre[w]; wpre[w] = a; a += t; }
    wtot = a;
  }
  __syncthreads();
  const int excl = x - v + wpre[wid];
  if (tid == 0) bs2[bidx] = wtot;
  gbar(bar, 2);

  // P2b: global offsets (16 blocks per batch; batch base = b*NPTS)
  const int bb = bidx >> 4;
  const int kk = bidx & 15;
  int off = bb * NPTS;
  for (int j = 0; j < kk; ++j)
    off += __hip_atomic_load(&bs2[bb * 16 + j], __ATOMIC_RELAXED, __HIP_MEMORY_SCOPE_AGENT);
  ranges[g] = make_int2(off + excl, v);
  cursor[g] = off + excl;
  gbar(bar, 3);

  // P3: scatter (cursor via device atomics; sorted read by next kernel)
  for (int i = bidx * BLD_NT + tid; i < NTOT; i += BLD_NB * BLD_NT) {
    const int b = i >> 13;
    const float x2 = pts[i * 3 + 0], y2 = pts[i * 3 + 1], z2 = pts[i * 3 + 2];
    const int c = ((b * GC + cellc(z2)) * GC + cellc(y2)) * GC + cellc(x2);
    const int pos = atomicAdd(&cursor[c], 1);
    sorted[pos] = make_float4(x2, y2, z2, fmaf(x2, x2, fmaf(y2, y2, z2 * z2)));
  }
}

// ============ search: one wave per point, tiered top-16 selection ============

template<int R>
__device__ __forceinline__ float tourney(const float* __restrict__ hq, int hn, int lane) {
  float v[R];
#pragma unroll
  for (int r = 0; r < R; ++r) {
    const int idx = lane + 64 * r;
    v[r] = (idx < hn) ? hq[idx] : BIGF;
  }
  if constexpr (R == 3) { CE(v[0], v[1]); CE(v[1], v[2]); CE(v[0], v[1]); }
  if constexpr (R == 6) {
    CE(v[0], v[1]); CE(v[2], v[3]); CE(v[4], v[5]);
    CE(v[1], v[2]); CE(v[3], v[4]);
    CE(v[0], v[1]); CE(v[2], v[3]); CE(v[4], v[5]);
    CE(v[1], v[2]); CE(v[3], v[4]);
    CE(v[0], v[1]); CE(v[2], v[3]); CE(v[4], v[5]);
    CE(v[1], v[2]); CE(v[3], v[4]);
  }
  float loss = 0.0f;
#pragma unroll
  for (int r = 0; r < NN; ++r) {
    float g = v[0];
    g = fminf(g, __shfl_xor(g, 1));
    g = fminf(g, __shfl_xor(g, 2));
    g = fminf(g, __shfl_xor(g, 4));
    g = fminf(g, __shfl_xor(g, 8));
    g = fminf(g, __shfl_xor(g, 16));
    g = fminf(g, __shfl_xor(g, 32));
    loss += prsqrt(g + EPSF);    // hn > NN here => all 16 mins are real in-radius hits
    const unsigned long long own = __ballot(v[0] == g);
    const int first = (int)(__ffsll((unsigned long long)own) - 1);
    if (lane == first) {
#pragma unroll
      for (int r2 = 0; r2 < R - 1; ++r2) v[r2] = v[r2 + 1];
      v[R - 1] = BIGF;
    }
  }
  return loss;
}

__global__ __launch_bounds__(STHR)
void search_kernel(const float4* __restrict__ sorted, const int2* __restrict__ rngs,
                   float* __restrict__ bsums) {
  __shared__ float hbuf[SWV][HCAP];     // 6 KB
  __shared__ float wloss[SWV];

  const int tid = threadIdx.x;
  const int wv = tid >> 6;
  const int lane = tid & 63;
  const int p = blockIdx.x * SWV + wv;
  const int bb = p >> 13;

  const float4 pt = sorted[p];
  const float m2x = -2.0f * pt.x, m2y = -2.0f * pt.y, m2z = -2.0f * pt.z;
  const float sp = pt.w;
  const int cx = cellc(pt.x), cy = cellc(pt.y), cz = cellc(pt.z);
  const int xlo = max(cx - 1, 0), xhi = min(cx + 1, GC - 1);

  float* hq = hbuf[wv];
  int hcnt = 0;

#pragma unroll
  for (int dz = -1; dz <= 1; ++dz) {
#pragma unroll
    for (int dy = -1; dy <= 1; ++dy) {
      const int czn = cz + dz, cyn = cy + dy;
      int s = 0, e = 0;
      if ((unsigned)czn < GC && (unsigned)cyn < GC) {   // wave-uniform
        const int cr = __builtin_amdgcn_readfirstlane(((bb * GC + czn) * GC + cyn) * GC);
        const int2 ra = rngs[cr + xlo];
        const int2 rb = rngs[cr + xhi];
        s = ra.x;
        e = rb.x + rb.y;
      }
      for (int j0 = s; j0 < e; j0 += 64) {
        const int j = j0 + lane;
        float d2 = BIGF;
        if (j < e) {
          const float4 q = sorted[j];
          d2 = fmaf(q.x, m2x, fmaf(q.y, m2y, fmaf(q.z, m2z, q.w + sp)));
        }
        // self excluded exactly by index (dot-form d2 not exactly 0 for self)
        const bool hit = (d2 < RAD2) && (j != p);
        const unsigned long long bal = __ballot(hit);
        const int pre = __builtin_amdgcn_mbcnt_hi(
            (unsigned)(bal >> 32), __builtin_amdgcn_mbcnt_lo((unsigned)bal, 0));
        const int pos = hcnt + pre;
        if (hit && pos < HCAP) hq[pos] = d2;
        hcnt += (int)__popcll(bal);
      }
    }
  }

  const int hn = min(hcnt, HCAP);   // uniform across wave
  float loss;
  if (hn <= NN) {
    // <=16 hits: every in-radius hit is among the 16 NN -> direct sum (~14% of pts)
    float l = (lane < hn) ? prsqrt(hq[lane] + EPSF) : 0.0f;
    l += __shfl_xor(l, 1);
    l += __shfl_xor(l, 2);
    l += __shfl_xor(l, 4);
    l += __shfl_xor(l, 8);
    l += __shfl_xor(l, 16);
    l += __shfl_xor(l, 32);
    loss = l;
  } else if (hn <= 64) {
    loss = tourney<1>(hq, hn, lane);   // ~29% of points
  } else if (hn <= 192) {
    loss = tourney<3>(hq, hn, lane);   // ~47% of points
  } else {
    loss = tourney<6>(hq, hn, lane);   // ~10% (dense center, up to ~330 hits)
  }

  if (lane == 0) wloss[wv] = loss;
  __syncthreads();
  if (tid == 0) {
    float s = 0.0f;
#pragma unroll
    for (int w = 0; w < SWV; ++w) s += wloss[w];
    bsums[blockIdx.x] = s;
  }
}

__global__ __launch_bounds__(256)
void finalize_kernel(const float* __restrict__ block_sums, int nblocks,
                     float* __restrict__ out) {
  __shared__ float s[256];
  float v = 0.0f;
  for (int idx = threadIdx.x; idx < nblocks; idx += 256) v += block_sums[idx];
  s[threadIdx.x] = v;
  __syncthreads();
  for (int off = 128; off > 0; off >>= 1) {
    if (threadIdx.x < off) s[threadIdx.x] += s[threadIdx.x + off];
    __syncthreads();
  }
  if (threadIdx.x == 0) out[0] = s[0] / (float)(NBATCH * NPTS * NN);
}

// ============ dense fallback (if ws too small) ============

#define DTILE 1024
#define DNT 512
#define DNW 8
#define DNB (NTOT / 64)
#define CSTRIDE 17
#define QTRIG 13

__device__ __forceinline__ void insert16(float (&td)[NN], float& thrmax, float v) {
  if (v < thrmax) {
    bool done = false;
#pragma unroll
    for (int k = 0; k < NN; ++k) {
      const bool hit = (!done) && (td[k] == thrmax);
      if (hit) td[k] = v;
      done = done || hit;
    }
    thrmax = td[0];
#pragma unroll
    for (int k = 1; k < NN; ++k) thrmax = fmaxf(thrmax, td[k]);
  }
}

__device__ __forceinline__ void drain_queue(float* buf, int qbase, int& cnt,
                                            float (&td)[NN], float& thrmax) {
#pragma unroll
  for (int c = 0; c < 16; ++c) {
    const float v = (c < cnt) ? buf[qbase + c] : BIGF;
    insert16(td, thrmax, v);
  }
  cnt = 0;
}

__global__ __launch_bounds__(DNT)
void dense_kernel(const float* __restrict__ pts, float* __restrict__ block_sums) {
  __shared__ float4 tile[DTILE];
  __shared__ float buf[DNT * CSTRIDE];

  const int tid = threadIdx.x;
  const int wave = tid >> 6;
  const int lane = tid & 63;
  const int bid = blockIdx.x;
  const int b = bid / (NPTS / 64);
  const int base = (bid % (NPTS / 64)) * 64;
  const float* __restrict__ bp = pts + (size_t)b * NPTS * 3;

  const int i = base + lane;
  const float xi = bp[i * 3 + 0];
  const float yi = bp[i * 3 + 1];
  const float zi = bp[i * 3 + 2];

  float td[NN];
#pragma unroll
  for (int k = 0; k < NN; ++k) td[k] = BIGF;
  float thrmax = BIGF;
  int cnt = 0;
  const int qbase = tid * CSTRIDE;

  for (int tb = 0; tb < NPTS; tb += DTILE) {
    for (int pp = tid; pp < DTILE; pp += DNT) {
      const float* sp = bp + (size_t)(tb + pp) * 3;
      tile[pp] = make_float4(sp[0], sp[1], sp[2], 0.0f);
    }
    __syncthreads();
    const int jb = wave * (DTILE / DNW);
    for (int jj = 0; jj < DTILE / DNW; ++jj) {
      const float4 q = tile[jb + jj];
      const float ddx = q.x - xi, ddy = q.y - yi, ddz = q.z - zi;
      const float d2 = fmaf(ddx, ddx, fmaf(ddy, ddy, ddz * ddz));
      if (d2 < RAD2 && d2 != 0.0f) {
        buf[qbase + cnt] = d2;
        ++cnt;
      }
      if (__any(cnt >= QTRIG)) drain_queue(buf, qbase, cnt, td, thrmax);
    }
    __syncthreads();
  }
  drain_queue(buf, qbase, cnt, td, thrmax);
#pragma unroll
  for (int k = 0; k < NN; ++k) buf[qbase + k] = td[k];
  __syncthreads();

  if (wave == 0) {
    float sd[NN];
#pragma unroll
    for (int k = 0; k < NN; ++k) sd[k] = BIGF;
    float smax = BIGF;
    for (int w = 0; w < DNW; ++w) {
      for (int c = 0; c < NN; ++c) {
        insert16(sd, smax, buf[(w * 64 + lane) * CSTRIDE + c]);
      }
    }
    float loss = 0.0f;
#pragma unroll
    for (int k = 0; k < NN; ++k) {
      if (sd[k] < RAD2) loss += 1.0f / sqrtf(sd[k] + EPSF);
    }
    for (int off = 32; off > 0; off >>= 1) loss += __shfl_down(loss, off);
    if (lane == 0) block_sums[bid] = loss;
  }
}

// ============ launch ============

extern "C" void kernel_launch(void* const* d_in, const int* in_sizes, int n_in,
                              void* d_out, int out_size, void* d_ws, size_t ws_size,
                              hipStream_t stream) {
  const float* pts = (const float*)d_in[0];
  float* out = (float*)d_out;
  char* ws = (char*)d_ws;

  if (ws_size >= (size_t)WS_NEEDED) {
    int* counts = (int*)(ws + WS_COUNTS);
    int2* rngs = (int2*)(ws + WS_RANGES);
    int* cursor = (int*)(ws + WS_CURSOR);
    float4* sorted = (float4*)(ws + WS_SORTED);
    float* bsums = (float*)(ws + WS_BSUMS);
    int* bs2 = (int*)(ws + WS_BS2);
    int* bar = (int*)(ws + WS_BAR);

    hipMemsetAsync(ws + WS_BAR, 0, 16, stream);   // reset spin-barrier counters
    build_kernel<<<BLD_NB, BLD_NT, 0, stream>>>(pts, counts, rngs, cursor, sorted, bs2, bar);
    search_kernel<<<SNB, STHR, 0, stream>>>(sorted, rngs, bsums);
    finalize_kernel<<<1, 256, 0, stream>>>(bsums, SNB, out);
  } else {
    float* bsums = (float*)ws;
    dense_kernel<<<DNB, DNT, 0, stream>>>(pts, bsums);
    finalize_kernel<<<1, 256, 0, stream>>>(bsums, DNB, out);
  }
}

// Round 9
// 66.868 us; speedup vs baseline: 5.2617x; 1.7237x over previous
//
#include <hip/hip_runtime.h>

#define NPTS 8192
#define NBATCH 4
#define NTOT (NBATCH * NPTS)     // 32768
#define NN 16
#define RAD2 0.25f
#define EPSF 1e-4f
#define BIGF 1e30f

// ---- grid: cell 0.5 over [-4,4), 16 real cells + ghost ring -> 18^3, x fastest ----
#define GC 16
#define GP 18
#define CBS 6144                  // padded per-batch cell stride (>= 18^3 = 5832)
#define NCELL_TOT (NBATCH * CBS)  // 24576

// ---- search: one wave per point ----
#define STHR 256
#define SWV 4
#define SNB (NTOT / SWV)          // 8192 blocks
#define HCAP 384                  // >= realized max in-RAD2 hits (~330); clamped pts <= 256

// adaptive radius: r0^3 = C / ncand with C = 2.5 * (12/pi) * 3.375 = 32.23
// (target ~40 in-r0 hits; exact fallback covers misestimates)
#define LOG2C 5.0103f
// clamp r0 to 0.5 exactly when ncand <= C / 0.5^3 = 257 (int condition, no float-eq)
#define NCLAMP 257

// ---- ws layout (bytes) ----
#define WS_COUNTS 0
#define WS_RANGES (WS_COUNTS + NCELL_TOT * 4)          // int2
#define WS_CURSOR (WS_RANGES + NCELL_TOT * 8)
#define WS_SORTED (WS_CURSOR + NCELL_TOT * 4)          // float4 (+64 pad)
#define WS_BSUMS  (WS_SORTED + (NTOT + 64) * 16)
#define WS_NEEDED (WS_BSUMS + SNB * 4)                 // ~951 KB

__device__ __forceinline__ int cellc(float v) {
  return min(max((int)floorf((v + 4.0f) * 2.0f), 0), GC - 1);
}

// refined rsqrt: v_rsq + one Newton step (~1-2 ulp; mean over 512K terms absorbs it)
__device__ __forceinline__ float prsqrt(float x) {
  float r = __builtin_amdgcn_rsqf(x);
  r = r * fmaf(-0.5f * x * r, r, 1.5f);
  return r;
}

#define CE(a, b) { const float lo_ = fminf(a, b); const float hi_ = fmaxf(a, b); a = lo_; b = hi_; }

// ============ build (R5-proven 4-kernel pipeline) ============

__global__ __launch_bounds__(256)
void zero_kernel(int* __restrict__ counts) {
  const int i = blockIdx.x * 256 + threadIdx.x;
  if (i < NCELL_TOT) counts[i] = 0;
}

__global__ __launch_bounds__(256)
void hist_kernel(const float* __restrict__ pts, int* __restrict__ counts) {
  const int i = blockIdx.x * 256 + threadIdx.x;
  if (i >= NTOT) return;
  const int b = i >> 13;
  const float x = pts[i * 3 + 0], y = pts[i * 3 + 1], z = pts[i * 3 + 2];
  const int c = b * CBS + ((cellc(z) + 1) * GP + (cellc(y) + 1)) * GP + (cellc(x) + 1);
  atomicAdd(&counts[c], 1);
}

__global__ __launch_bounds__(1024)
void scan_kernel(const int* __restrict__ counts, int2* __restrict__ ranges,
                 int* __restrict__ cursor) {
  __shared__ int wsum[16];
  __shared__ int woff[16];
  __shared__ int stot;
  const int b = blockIdx.x;
  const int tid = threadIdx.x;
  const int wid = tid >> 6;
  const int lane = tid & 63;
  const int g0 = b * CBS;
  int running = b * NPTS;
  for (int chunk = 0; chunk < CBS; chunk += 1024) {
    const int idx = chunk + tid;
    const int v = counts[g0 + idx];
    int x = v;
    for (int off = 1; off < 64; off <<= 1) {
      const int t = __shfl_up(x, off, 64);
      if (lane >= off) x += t;
    }
    if (lane == 63) wsum[wid] = x;
    __syncthreads();
    if (wid == 0) {
      int s = (lane < 16) ? wsum[lane] : 0;
      for (int off = 1; off < 16; off <<= 1) {
        const int t = __shfl_up(s, off, 64);
        if (lane >= off) s += t;
      }
      if (lane < 16) woff[lane] = s - wsum[lane];
      if (lane == 15) stot = s;
    }
    __syncthreads();
    const int excl = running + woff[wid] + x - v;
    ranges[g0 + idx] = make_int2(excl, v);
    cursor[g0 + idx] = excl;
    running += stot;
    __syncthreads();
  }
}

__global__ __launch_bounds__(256)
void scatter_kernel(const float* __restrict__ pts, int* __restrict__ cursor,
                    float4* __restrict__ sorted) {
  const int i = blockIdx.x * 256 + threadIdx.x;
  if (i >= NTOT) return;
  const int b = i >> 13;
  const float x = pts[i * 3 + 0], y = pts[i * 3 + 1], z = pts[i * 3 + 2];
  const int c = b * CBS + ((cellc(z) + 1) * GP + (cellc(y) + 1)) * GP + (cellc(x) + 1);
  const int pos = atomicAdd(&cursor[c], 1);
  sorted[pos] = make_float4(x, y, z, fmaf(x, x, fmaf(y, y, z * z)));
}

// ============ search: wave=point, adaptive radius, bitonic extraction ============

template<int R>
__device__ __forceinline__ float tourney(const float* __restrict__ hq, int hn, int lane) {
  float v[R];
#pragma unroll
  for (int r = 0; r < R; ++r) {
    const int idx = lane + 64 * r;
    v[r] = (idx < hn) ? hq[idx] : BIGF;
  }
  if constexpr (R == 3) { CE(v[0], v[1]); CE(v[1], v[2]); CE(v[0], v[1]); }
  if constexpr (R == 6) {
    CE(v[0], v[1]); CE(v[2], v[3]); CE(v[4], v[5]);
    CE(v[1], v[2]); CE(v[3], v[4]);
    CE(v[0], v[1]); CE(v[2], v[3]); CE(v[4], v[5]);
    CE(v[1], v[2]); CE(v[3], v[4]);
    CE(v[0], v[1]); CE(v[2], v[3]); CE(v[4], v[5]);
    CE(v[1], v[2]); CE(v[3], v[4]);
  }
  float loss = 0.0f;
#pragma unroll
  for (int r = 0; r < NN; ++r) {
    float g = v[0];
    g = fminf(g, __shfl_xor(g, 1));
    g = fminf(g, __shfl_xor(g, 2));
    g = fminf(g, __shfl_xor(g, 4));
    g = fminf(g, __shfl_xor(g, 8));
    g = fminf(g, __shfl_xor(g, 16));
    g = fminf(g, __shfl_xor(g, 32));
    loss += prsqrt(g + EPSF);    // hn > 64 here => all 16 mins real, < RAD2
    const unsigned long long own = __ballot(v[0] == g);
    const int first = (int)(__ffsll((unsigned long long)own) - 1);
    if (lane == first) {
#pragma unroll
      for (int r2 = 0; r2 < R - 1; ++r2) v[r2] = v[r2 + 1];
      v[R - 1] = BIGF;
    }
  }
  return loss;
}

__global__ __launch_bounds__(STHR)
void search_kernel(const float4* __restrict__ sorted, const int2* __restrict__ rngs,
                   float* __restrict__ bsums) {
  __shared__ float hbuf[SWV][HCAP];     // 6 KB
  __shared__ float wloss[SWV];

  const int tid = threadIdx.x;
  const int wv = tid >> 6;
  const int lane = tid & 63;
  const int p = blockIdx.x * SWV + wv;
  const int bb = p >> 13;

  const float4 pt = sorted[p];
  const float m2x = -2.0f * pt.x, m2y = -2.0f * pt.y, m2z = -2.0f * pt.z;
  const float sp = pt.w;
  const int cx = cellc(pt.x), cy = cellc(pt.y), cz = cellc(pt.z);
  // wave-uniform; pin to SGPR so the 18 range loads become scalar loads
  const int c0 = __builtin_amdgcn_readfirstlane(
      bb * CBS + ((cz + 1) * GP + (cy + 1)) * GP + (cx + 1));

  const int rowoff[9] = {
    (-1 * GP - 1) * GP, (-1 * GP + 0) * GP, (-1 * GP + 1) * GP,
    ( 0 * GP - 1) * GP, ( 0 * GP + 0) * GP, ( 0 * GP + 1) * GP,
    ( 1 * GP - 1) * GP, ( 1 * GP + 0) * GP, ( 1 * GP + 1) * GP };

  int rs[9], re[9];
  int ncand = 0;
#pragma unroll
  for (int m = 0; m < 9; ++m) {
    const int2 a = rngs[c0 + rowoff[m] - 1];   // dx=-1 cell (ghost-safe)
    const int2 e2 = rngs[c0 + rowoff[m] + 1];  // dx=+1 cell
    rs[m] = a.x;
    re[m] = e2.x + e2.y;
    ncand += re[m] - rs[m];
  }

  // adaptive collect radius
  const bool clamped = (ncand <= NCLAMP);
  float r0sq = RAD2;
  if (!clamped) {
    r0sq = exp2f((LOG2C - log2f((float)ncand)) * (2.0f / 3.0f));
  }

  float* hq = hbuf[wv];
  int hcnt = 0;

#define SCAN_ROWS(RR) {                                                         \
    hcnt = 0;                                                                   \
    _Pragma("unroll")                                                           \
    for (int m = 0; m < 9; ++m) {                                               \
      const int s = rs[m], e = re[m];                                           \
      for (int j0 = s; j0 < e; j0 += 64) {                                      \
        const int j = j0 + lane;                                                \
        float d2 = BIGF;                                                        \
        if (j < e) {                                                            \
          const float4 q = sorted[j];                                           \
          d2 = fmaf(q.x, m2x, fmaf(q.y, m2y, fmaf(q.z, m2z, q.w + sp)));        \
        }                                                                       \
        bool hit = (d2 < (RR));                                                 \
        if (m == 4) hit = hit && (j != p);   /* exact self-exclusion */         \
        const unsigned long long bal = __ballot(hit);                           \
        const int pre = __builtin_amdgcn_mbcnt_hi(                              \
            (unsigned)(bal >> 32), __builtin_amdgcn_mbcnt_lo((unsigned)bal, 0));\
        const int pos = hcnt + pre;                                             \
        if (hit && pos < HCAP) hq[pos] = d2;                                    \
        hcnt += (int)__popcll(bal);                                             \
      }                                                                         \
    }                                                                           \
  }

  SCAN_ROWS(r0sq);
  int hn = min(hcnt, HCAP);
  // if fewer than 16 within r0 and r0 < RAD2, rescan at full radius (rare)
  if (hn < NN && !clamped) {
    SCAN_ROWS(RAD2);
    hn = min(hcnt, HCAP);
  }

  float loss;
  if (hn <= 64) {
    // bitonic sort 64 values across lanes, then sum 16 smallest
    float v = (lane < hn) ? hq[lane] : BIGF;
#pragma unroll
    for (int k = 2; k <= 64; k <<= 1) {
#pragma unroll
      for (int j = k >> 1; j > 0; j >>= 1) {
        const float o = __shfl_xor(v, j, 64);
        const bool keepmin = (((lane & j) == 0) != ((lane & k) != 0));
        v = keepmin ? fminf(v, o) : fmaxf(v, o);
      }
    }
    float l = (lane < NN && v < RAD2) ? prsqrt(v + EPSF) : 0.0f;
    l += __shfl_xor(l, 1);
    l += __shfl_xor(l, 2);
    l += __shfl_xor(l, 4);
    l += __shfl_xor(l, 8);
    l += __shfl_xor(l, 16);
    l += __shfl_xor(l, 32);
    loss = l;
  } else if (hn <= 192) {
    loss = tourney<3>(hq, hn, lane);
  } else {
    loss = tourney<6>(hq, hn, lane);
  }

  if (lane == 0) wloss[wv] = loss;
  __syncthreads();
  if (tid == 0) {
    float s = 0.0f;
#pragma unroll
    for (int w = 0; w < SWV; ++w) s += wloss[w];
    bsums[blockIdx.x] = s;
  }
}

__global__ __launch_bounds__(256)
void finalize_kernel(const float* __restrict__ block_sums, int nblocks,
                     float* __restrict__ out) {
  __shared__ float s[256];
  float v = 0.0f;
  for (int idx = threadIdx.x; idx < nblocks; idx += 256) v += block_sums[idx];
  s[threadIdx.x] = v;
  __syncthreads();
  for (int off = 128; off > 0; off >>= 1) {
    if (threadIdx.x < off) s[threadIdx.x] += s[threadIdx.x + off];
    __syncthreads();
  }
  if (threadIdx.x == 0) out[0] = s[0] / (float)(NBATCH * NPTS * NN);
}

// ============ dense fallback (if ws too small) ============

#define DTILE 1024
#define DNT 512
#define DNW 8
#define DNB (NTOT / 64)
#define CSTRIDE 17
#define QTRIG 13

__device__ __forceinline__ void insert16(float (&td)[NN], float& thrmax, float v) {
  if (v < thrmax) {
    bool done = false;
#pragma unroll
    for (int k = 0; k < NN; ++k) {
      const bool hit = (!done) && (td[k] == thrmax);
      if (hit) td[k] = v;
      done = done || hit;
    }
    thrmax = td[0];
#pragma unroll
    for (int k = 1; k < NN; ++k) thrmax = fmaxf(thrmax, td[k]);
  }
}

__device__ __forceinline__ void drain_queue(float* buf, int qbase, int& cnt,
                                            float (&td)[NN], float& thrmax) {
#pragma unroll
  for (int c = 0; c < 16; ++c) {
    const float v = (c < cnt) ? buf[qbase + c] : BIGF;
    insert16(td, thrmax, v);
  }
  cnt = 0;
}

__global__ __launch_bounds__(DNT)
void dense_kernel(const float* __restrict__ pts, float* __restrict__ block_sums) {
  __shared__ float4 tile[DTILE];
  __shared__ float buf[DNT * CSTRIDE];

  const int tid = threadIdx.x;
  const int wave = tid >> 6;
  const int lane = tid & 63;
  const int bid = blockIdx.x;
  const int b = bid / (NPTS / 64);
  const int base = (bid % (NPTS / 64)) * 64;
  const float* __restrict__ bp = pts + (size_t)b * NPTS * 3;

  const int i = base + lane;
  const float xi = bp[i * 3 + 0];
  const float yi = bp[i * 3 + 1];
  const float zi = bp[i * 3 + 2];

  float td[NN];
#pragma unroll
  for (int k = 0; k < NN; ++k) td[k] = BIGF;
  float thrmax = BIGF;
  int cnt = 0;
  const int qbase = tid * CSTRIDE;

  for (int tb = 0; tb < NPTS; tb += DTILE) {
    for (int pp = tid; pp < DTILE; pp += DNT) {
      const float* sp = bp + (size_t)(tb + pp) * 3;
      tile[pp] = make_float4(sp[0], sp[1], sp[2], 0.0f);
    }
    __syncthreads();
    const int jb = wave * (DTILE / DNW);
    for (int jj = 0; jj < DTILE / DNW; ++jj) {
      const float4 q = tile[jb + jj];
      const float ddx = q.x - xi, ddy = q.y - yi, ddz = q.z - zi;
      const float d2 = fmaf(ddx, ddx, fmaf(ddy, ddy, ddz * ddz));
      if (d2 < RAD2 && d2 != 0.0f) {
        buf[qbase + cnt] = d2;
        ++cnt;
      }
      if (__any(cnt >= QTRIG)) drain_queue(buf, qbase, cnt, td, thrmax);
    }
    __syncthreads();
  }
  drain_queue(buf, qbase, cnt, td, thrmax);
#pragma unroll
  for (int k = 0; k < NN; ++k) buf[qbase + k] = td[k];
  __syncthreads();

  if (wave == 0) {
    float sd[NN];
#pragma unroll
    for (int k = 0; k < NN; ++k) sd[k] = BIGF;
    float smax = BIGF;
    for (int w = 0; w < DNW; ++w) {
      for (int c = 0; c < NN; ++c) {
        insert16(sd, smax, buf[(w * 64 + lane) * CSTRIDE + c]);
      }
    }
    float loss = 0.0f;
#pragma unroll
    for (int k = 0; k < NN; ++k) {
      if (sd[k] < RAD2) loss += 1.0f / sqrtf(sd[k] + EPSF);
    }
    for (int off = 32; off > 0; off >>= 1) loss += __shfl_down(loss, off);
    if (lane == 0) block_sums[bid] = loss;
  }
}

// ============ launch ============

extern "C" void kernel_launch(void* const* d_in, const int* in_sizes, int n_in,
                              void* d_out, int out_size, void* d_ws, size_t ws_size,
                              hipStream_t stream) {
  const float* pts = (const float*)d_in[0];
  float* out = (float*)d_out;
  char* ws = (char*)d_ws;

  if (ws_size >= (size_t)WS_NEEDED) {
    int* counts = (int*)(ws + WS_COUNTS);
    int2* rngs = (int2*)(ws + WS_RANGES);
    int* cursor = (int*)(ws + WS_CURSOR);
    float4* sorted = (float4*)(ws + WS_SORTED);
    float* bsums = (float*)(ws + WS_BSUMS);

    zero_kernel<<<(NCELL_TOT + 255) / 256, 256, 0, stream>>>(counts);
    hist_kernel<<<(NTOT + 255) / 256, 256, 0, stream>>>(pts, counts);
    scan_kernel<<<NBATCH, 1024, 0, stream>>>(counts, rngs, cursor);
    scatter_kernel<<<(NTOT + 255) / 256, 256, 0, stream>>>(pts, cursor, sorted);
    search_kernel<<<SNB, STHR, 0, stream>>>(sorted, rngs, bsums);
    finalize_kernel<<<1, 256, 0, stream>>>(bsums, SNB, out);
  } else {
    float* bsums = (float*)ws;
    dense_kernel<<<DNB, DNT, 0, stream>>>(pts, bsums);
    finalize_kernel<<<1, 256, 0, stream>>>(bsums, DNB, out);
  }
}

// Round 10
// 65.259 us; speedup vs baseline: 5.3914x; 1.0247x over previous
//
#include <hip/hip_runtime.h>

#define NPTS 8192
#define NBATCH 4
#define NTOT (NBATCH * NPTS)     // 32768
#define NN 16
#define RAD2 0.25f
#define EPSF 1e-4f
#define BIGF 1e30f

// ---- grid: cell 0.5 over [-4,4), 16 real cells + ghost ring -> 18^3, x fastest ----
#define GC 16
#define GP 18
#define CBS 6144                  // padded per-batch cell stride (>= 18^3 = 5832)
#define NCELL_TOT (NBATCH * CBS)  // 24576

// ---- search: one wave per TWO consecutive (cell-sorted) points ----
#define STHR 256
#define SWV 4
#define PPW 2
#define SNB (NTOT / (SWV * PPW))  // 4096 blocks
#define HCAP 384                  // >= realized max in-RAD2 hits (~330)

// adaptive radius: r0^3 = C / ncand, C = 2.5*(12/pi)*3.375 = 32.23 (target ~40 hits)
#define LOG2C 5.0103f
#define NCLAMP 257                // ncand <= 257 -> r0 clamped to full radius

// ---- ws layout (bytes) ----
#define WS_COUNTS 0
#define WS_RANGES (WS_COUNTS + NCELL_TOT * 4)          // int2
#define WS_CURSOR (WS_RANGES + NCELL_TOT * 8)
#define WS_SORTED (WS_CURSOR + NCELL_TOT * 4)          // float4 (+64 pad)
#define WS_BSUMS  (WS_SORTED + (NTOT + 64) * 16)
#define WS_NEEDED (WS_BSUMS + SNB * 4)

__device__ __forceinline__ int cellc(float v) {
  return min(max((int)floorf((v + 4.0f) * 2.0f), 0), GC - 1);
}

// refined rsqrt: v_rsq + one Newton step (~1-2 ulp; mean over 512K terms absorbs it)
__device__ __forceinline__ float prsqrt(float x) {
  float r = __builtin_amdgcn_rsqf(x);
  r = r * fmaf(-0.5f * x * r, r, 1.5f);
  return r;
}

__device__ __forceinline__ int lanepre(unsigned long long m) {
  return __builtin_amdgcn_mbcnt_hi((unsigned)(m >> 32),
         __builtin_amdgcn_mbcnt_lo((unsigned)m, 0));
}

#define CE(a, b) { const float lo_ = fminf(a, b); const float hi_ = fmaxf(a, b); a = lo_; b = hi_; }

// ============ build (R5/R9-proven 4-kernel pipeline) ============

__global__ __launch_bounds__(256)
void zero_kernel(int* __restrict__ counts) {
  const int i = blockIdx.x * 256 + threadIdx.x;
  if (i < NCELL_TOT) counts[i] = 0;
}

__global__ __launch_bounds__(256)
void hist_kernel(const float* __restrict__ pts, int* __restrict__ counts) {
  const int i = blockIdx.x * 256 + threadIdx.x;
  if (i >= NTOT) return;
  const int b = i >> 13;
  const float x = pts[i * 3 + 0], y = pts[i * 3 + 1], z = pts[i * 3 + 2];
  const int c = b * CBS + ((cellc(z) + 1) * GP + (cellc(y) + 1)) * GP + (cellc(x) + 1);
  atomicAdd(&counts[c], 1);
}

__global__ __launch_bounds__(1024)
void scan_kernel(const int* __restrict__ counts, int2* __restrict__ ranges,
                 int* __restrict__ cursor) {
  __shared__ int wsum[16];
  __shared__ int woff[16];
  __shared__ int stot;
  const int b = blockIdx.x;
  const int tid = threadIdx.x;
  const int wid = tid >> 6;
  const int lane = tid & 63;
  const int g0 = b * CBS;
  int running = b * NPTS;
  for (int chunk = 0; chunk < CBS; chunk += 1024) {
    const int idx = chunk + tid;
    const int v = counts[g0 + idx];
    int x = v;
    for (int off = 1; off < 64; off <<= 1) {
      const int t = __shfl_up(x, off, 64);
      if (lane >= off) x += t;
    }
    if (lane == 63) wsum[wid] = x;
    __syncthreads();
    if (wid == 0) {
      int s = (lane < 16) ? wsum[lane] : 0;
      for (int off = 1; off < 16; off <<= 1) {
        const int t = __shfl_up(s, off, 64);
        if (lane >= off) s += t;
      }
      if (lane < 16) woff[lane] = s - wsum[lane];
      if (lane == 15) stot = s;
    }
    __syncthreads();
    const int excl = running + woff[wid] + x - v;
    ranges[g0 + idx] = make_int2(excl, v);
    cursor[g0 + idx] = excl;
    running += stot;
    __syncthreads();
  }
}

__global__ __launch_bounds__(256)
void scatter_kernel(const float* __restrict__ pts, int* __restrict__ cursor,
                    float4* __restrict__ sorted) {
  const int i = blockIdx.x * 256 + threadIdx.x;
  if (i >= NTOT) return;
  const int b = i >> 13;
  const float x = pts[i * 3 + 0], y = pts[i * 3 + 1], z = pts[i * 3 + 2];
  const int c = b * CBS + ((cellc(z) + 1) * GP + (cellc(y) + 1)) * GP + (cellc(x) + 1);
  const int pos = atomicAdd(&cursor[c], 1);
  sorted[pos] = make_float4(x, y, z, fmaf(x, x, fmaf(y, y, z * z)));
}

// ============ search helpers ============

// scan 9 rows [rs,re) for one point; ballot-compact hits (< rr, j != selfp) into hq
__device__ __forceinline__ int scan1(const float4* __restrict__ sorted,
    const int* rs, const int* re, float rr, int selfp,
    float m2x, float m2y, float m2z, float sp, float* __restrict__ hq, int lane) {
  int hcnt = 0;
#pragma unroll
  for (int m = 0; m < 9; ++m) {
    const int s = rs[m], e = re[m];
    for (int j0 = s; j0 < e; j0 += 64) {
      const int j = j0 + lane;
      float d2 = BIGF;
      if (j < e) {
        const float4 q = sorted[j];
        d2 = fmaf(q.x, m2x, fmaf(q.y, m2y, fmaf(q.z, m2z, q.w + sp)));
      }
      const bool hit = (d2 < rr) && (j != selfp);
      const unsigned long long bal = __ballot(hit);
      const int pos = hcnt + lanepre(bal & ((1ull << lane) - 1ull) ? bal & ((1ull << lane) - 1ull) : 0ull);
      // (lanepre counts bits below lane; pass masked ballot)
      const int pre = __popcll(bal & ((1ull << lane) - 1ull));
      const int p2 = hcnt + pre;
      if (hit && p2 < HCAP) hq[p2] = d2;
      hcnt += (int)__popcll(bal);
      (void)pos;
    }
  }
  return hcnt;
}

// scan 9 shared rows once; score both points per candidate
__device__ __forceinline__ void scan2(const float4* __restrict__ sorted,
    const int* rs, const int* re, float rr,
    int pA, float m2xA, float m2yA, float m2zA, float spA,
    int pB, float m2xB, float m2yB, float m2zB, float spB,
    float* __restrict__ hqA, float* __restrict__ hqB, int lane,
    int& hcntA, int& hcntB) {
  int hA = 0, hB = 0;
#pragma unroll
  for (int m = 0; m < 9; ++m) {
    const int s = rs[m], e = re[m];
    for (int j0 = s; j0 < e; j0 += 64) {
      const int j = j0 + lane;
      float d2A = BIGF, d2B = BIGF;
      if (j < e) {
        const float4 q = sorted[j];
        const float qw = q.w;
        d2A = fmaf(q.x, m2xA, fmaf(q.y, m2yA, fmaf(q.z, m2zA, qw + spA)));
        d2B = fmaf(q.x, m2xB, fmaf(q.y, m2yB, fmaf(q.z, m2zB, qw + spB)));
      }
      const unsigned long long below = (1ull << lane) - 1ull;
      const bool hitA = (d2A < rr) && (j != pA);
      const unsigned long long balA = __ballot(hitA);
      const int posA = hA + (int)__popcll(balA & below);
      if (hitA && posA < HCAP) hqA[posA] = d2A;
      hA += (int)__popcll(balA);
      const bool hitB = (d2B < rr) && (j != pB);
      const unsigned long long balB = __ballot(hitB);
      const int posB = hB + (int)__popcll(balB & below);
      if (hitB && posB < HCAP) hqB[posB] = d2B;
      hB += (int)__popcll(balB);
    }
  }
  hcntA = hA;
  hcntB = hB;
}

template<int R>
__device__ __forceinline__ float tourney(const float* __restrict__ hq, int hn, int lane) {
  float v[R];
#pragma unroll
  for (int r = 0; r < R; ++r) {
    const int idx = lane + 64 * r;
    v[r] = (idx < hn) ? hq[idx] : BIGF;
  }
  if constexpr (R == 3) { CE(v[0], v[1]); CE(v[1], v[2]); CE(v[0], v[1]); }
  if constexpr (R == 6) {
    CE(v[0], v[1]); CE(v[2], v[3]); CE(v[4], v[5]);
    CE(v[1], v[2]); CE(v[3], v[4]);
    CE(v[0], v[1]); CE(v[2], v[3]); CE(v[4], v[5]);
    CE(v[1], v[2]); CE(v[3], v[4]);
    CE(v[0], v[1]); CE(v[2], v[3]); CE(v[4], v[5]);
    CE(v[1], v[2]); CE(v[3], v[4]);
  }
  float loss = 0.0f;
#pragma unroll
  for (int r = 0; r < NN; ++r) {
    float g = v[0];
    g = fminf(g, __shfl_xor(g, 1));
    g = fminf(g, __shfl_xor(g, 2));
    g = fminf(g, __shfl_xor(g, 4));
    g = fminf(g, __shfl_xor(g, 8));
    g = fminf(g, __shfl_xor(g, 16));
    g = fminf(g, __shfl_xor(g, 32));
    loss += prsqrt(g + EPSF);    // hn > 64 here => all 16 mins real, < RAD2
    const unsigned long long own = __ballot(v[0] == g);
    const int first = (int)(__ffsll((unsigned long long)own) - 1);
    if (lane == first) {
#pragma unroll
      for (int r2 = 0; r2 < R - 1; ++r2) v[r2] = v[r2 + 1];
      v[R - 1] = BIGF;
    }
  }
  return loss;
}

__device__ __forceinline__ float extract_loss(const float* __restrict__ hq, int hn, int lane) {
  if (hn <= 64) {
    // bitonic sort 64 across lanes, then sum the 16 smallest real hits
    float v = (lane < hn) ? hq[lane] : BIGF;
#pragma unroll
    for (int k = 2; k <= 64; k <<= 1) {
#pragma unroll
      for (int j = k >> 1; j > 0; j >>= 1) {
        const float o = __shfl_xor(v, j, 64);
        const bool keepmin = (((lane & j) == 0) != ((lane & k) != 0));
        v = keepmin ? fminf(v, o) : fmaxf(v, o);
      }
    }
    float l = (lane < NN && v < RAD2) ? prsqrt(v + EPSF) : 0.0f;
    l += __shfl_xor(l, 1);
    l += __shfl_xor(l, 2);
    l += __shfl_xor(l, 4);
    l += __shfl_xor(l, 8);
    l += __shfl_xor(l, 16);
    l += __shfl_xor(l, 32);
    return l;
  } else if (hn <= 192) {
    return tourney<3>(hq, hn, lane);
  }
  return tourney<6>(hq, hn, lane);
}

// ============ search: wave = 2 consecutive cell-sorted points ============

__global__ __launch_bounds__(STHR)
void search_kernel(const float4* __restrict__ sorted, const int2* __restrict__ rngs,
                   float* __restrict__ bsums) {
  __shared__ float hbuf[SWV][2][HCAP];   // 12.3 KB
  __shared__ float wloss[SWV];

  const int tid = threadIdx.x;
  const int wv = tid >> 6;
  const int lane = tid & 63;
  const int p0 = (blockIdx.x * SWV + wv) * 2;
  const int p1 = p0 + 1;
  const int bb = p0 >> 13;               // pairs never straddle batches (8192 even)

  const float4 ptA = sorted[p0];
  const float4 ptB = sorted[p1];
  const float m2xA = -2.0f * ptA.x, m2yA = -2.0f * ptA.y, m2zA = -2.0f * ptA.z;
  const float spA = ptA.w;
  const float m2xB = -2.0f * ptB.x, m2yB = -2.0f * ptB.y, m2zB = -2.0f * ptB.z;
  const float spB = ptB.w;

  const int rbA = __builtin_amdgcn_readfirstlane(
      bb * CBS + ((cellc(ptA.z) + 1) * GP + (cellc(ptA.y) + 1)) * GP);
  const int rbB = __builtin_amdgcn_readfirstlane(
      bb * CBS + ((cellc(ptB.z) + 1) * GP + (cellc(ptB.y) + 1)) * GP);
  const int xA = __builtin_amdgcn_readfirstlane(cellc(ptA.x));
  const int xB = __builtin_amdgcn_readfirstlane(cellc(ptB.x));

  const int rowoff[9] = {
    (-1 * GP - 1) * GP, (-1 * GP + 0) * GP, (-1 * GP + 1) * GP,
    ( 0 * GP - 1) * GP, ( 0 * GP + 0) * GP, ( 0 * GP + 1) * GP,
    ( 1 * GP - 1) * GP, ( 1 * GP + 0) * GP, ( 1 * GP + 1) * GP };

  float* hqA = hbuf[wv][0];
  float* hqB = hbuf[wv][1];
  int hnA, hnB;

  if (rbA == rbB) {
    // shared/union path (~98% of pairs): ghost x-window [min, max+2]
    const int lo = min(xA, xB);
    const int hi = max(xA, xB) + 2;
    int rs[9], re[9], ncand = 0;
#pragma unroll
    for (int m = 0; m < 9; ++m) {
      const int base = rbA + rowoff[m];
      const int2 a = rngs[base + lo];
      const int2 b = rngs[base + hi];
      rs[m] = a.x;
      re[m] = b.x + b.y;
      ncand += re[m] - rs[m];
    }
    const bool clamped = (ncand <= NCLAMP);
    float r0sq = RAD2;
    if (!clamped) r0sq = exp2f((LOG2C - log2f((float)ncand)) * (2.0f / 3.0f));

    int hA, hB;
    scan2(sorted, rs, re, r0sq, p0, m2xA, m2yA, m2zA, spA,
          p1, m2xB, m2yB, m2zB, spB, hqA, hqB, lane, hA, hB);
    hnA = min(hA, HCAP);
    hnB = min(hB, HCAP);
    // rare rescans at full radius (union rows are a safe superset for each point)
    if (hnA < NN && !clamped)
      hnA = min(scan1(sorted, rs, re, RAD2, p0, m2xA, m2yA, m2zA, spA, hqA, lane), HCAP);
    if (hnB < NN && !clamped)
      hnB = min(scan1(sorted, rs, re, RAD2, p1, m2xB, m2yB, m2zB, spB, hqB, lane), HCAP);
  } else {
    // row-straddle (~1-2%): two independent solo scans
    int rsA[9], reA[9], ncA = 0, rsB[9], reB[9], ncB = 0;
#pragma unroll
    for (int m = 0; m < 9; ++m) {
      const int baseA = rbA + rowoff[m];
      const int2 a0 = rngs[baseA + xA];
      const int2 a1 = rngs[baseA + xA + 2];
      rsA[m] = a0.x; reA[m] = a1.x + a1.y; ncA += reA[m] - rsA[m];
      const int baseB = rbB + rowoff[m];
      const int2 b0 = rngs[baseB + xB];
      const int2 b1 = rngs[baseB + xB + 2];
      rsB[m] = b0.x; reB[m] = b1.x + b1.y; ncB += reB[m] - rsB[m];
    }
    const bool clA = (ncA <= NCLAMP);
    const bool clB = (ncB <= NCLAMP);
    float rA = RAD2, rB = RAD2;
    if (!clA) rA = exp2f((LOG2C - log2f((float)ncA)) * (2.0f / 3.0f));
    if (!clB) rB = exp2f((LOG2C - log2f((float)ncB)) * (2.0f / 3.0f));
    hnA = min(scan1(sorted, rsA, reA, rA, p0, m2xA, m2yA, m2zA, spA, hqA, lane), HCAP);
    if (hnA < NN && !clA)
      hnA = min(scan1(sorted, rsA, reA, RAD2, p0, m2xA, m2yA, m2zA, spA, hqA, lane), HCAP);
    hnB = min(scan1(sorted, rsB, reB, rB, p1, m2xB, m2yB, m2zB, spB, hqB, lane), HCAP);
    if (hnB < NN && !clB)
      hnB = min(scan1(sorted, rsB, reB, RAD2, p1, m2xB, m2yB, m2zB, spB, hqB, lane), HCAP);
  }

  const float lossA = extract_loss(hqA, hnA, lane);
  const float lossB = extract_loss(hqB, hnB, lane);

  if (lane == 0) wloss[wv] = lossA + lossB;
  __syncthreads();
  if (tid == 0) {
    float s = 0.0f;
#pragma unroll
    for (int w = 0; w < SWV; ++w) s += wloss[w];
    bsums[blockIdx.x] = s;
  }
}

__global__ __launch_bounds__(256)
void finalize_kernel(const float* __restrict__ block_sums, int nblocks,
                     float* __restrict__ out) {
  __shared__ float s[256];
  float v = 0.0f;
  for (int idx = threadIdx.x; idx < nblocks; idx += 256) v += block_sums[idx];
  s[threadIdx.x] = v;
  __syncthreads();
  for (int off = 128; off > 0; off >>= 1) {
    if (threadIdx.x < off) s[threadIdx.x] += s[threadIdx.x + off];
    __syncthreads();
  }
  if (threadIdx.x == 0) out[0] = s[0] / (float)(NBATCH * NPTS * NN);
}

// ============ dense fallback (if ws too small) ============

#define DTILE 1024
#define DNT 512
#define DNW 8
#define DNB (NTOT / 64)
#define CSTRIDE 17
#define QTRIG 13

__device__ __forceinline__ void insert16(float (&td)[NN], float& thrmax, float v) {
  if (v < thrmax) {
    bool done = false;
#pragma unroll
    for (int k = 0; k < NN; ++k) {
      const bool hit = (!done) && (td[k] == thrmax);
      if (hit) td[k] = v;
      done = done || hit;
    }
    thrmax = td[0];
#pragma unroll
    for (int k = 1; k < NN; ++k) thrmax = fmaxf(thrmax, td[k]);
  }
}

__device__ __forceinline__ void drain_queue(float* buf, int qbase, int& cnt,
                                            float (&td)[NN], float& thrmax) {
#pragma unroll
  for (int c = 0; c < 16; ++c) {
    const float v = (c < cnt) ? buf[qbase + c] : BIGF;
    insert16(td, thrmax, v);
  }
  cnt = 0;
}

__global__ __launch_bounds__(DNT)
void dense_kernel(const float* __restrict__ pts, float* __restrict__ block_sums) {
  __shared__ float4 tile[DTILE];
  __shared__ float buf[DNT * CSTRIDE];

  const int tid = threadIdx.x;
  const int wave = tid >> 6;
  const int lane = tid & 63;
  const int bid = blockIdx.x;
  const int b = bid / (NPTS / 64);
  const int base = (bid % (NPTS / 64)) * 64;
  const float* __restrict__ bp = pts + (size_t)b * NPTS * 3;

  const int i = base + lane;
  const float xi = bp[i * 3 + 0];
  const float yi = bp[i * 3 + 1];
  const float zi = bp[i * 3 + 2];

  float td[NN];
#pragma unroll
  for (int k = 0; k < NN; ++k) td[k] = BIGF;
  float thrmax = BIGF;
  int cnt = 0;
  const int qbase = tid * CSTRIDE;

  for (int tb = 0; tb < NPTS; tb += DTILE) {
    for (int pp = tid; pp < DTILE; pp += DNT) {
      const float* sp = bp + (size_t)(tb + pp) * 3;
      tile[pp] = make_float4(sp[0], sp[1], sp[2], 0.0f);
    }
    __syncthreads();
    const int jb = wave * (DTILE / DNW);
    for (int jj = 0; jj < DTILE / DNW; ++jj) {
      const float4 q = tile[jb + jj];
      const float ddx = q.x - xi, ddy = q.y - yi, ddz = q.z - zi;
      const float d2 = fmaf(ddx, ddx, fmaf(ddy, ddy, ddz * ddz));
      if (d2 < RAD2 && d2 != 0.0f) {
        buf[qbase + cnt] = d2;
        ++cnt;
      }
      if (__any(cnt >= QTRIG)) drain_queue(buf, qbase, cnt, td, thrmax);
    }
    __syncthreads();
  }
  drain_queue(buf, qbase, cnt, td, thrmax);
#pragma unroll
  for (int k = 0; k < NN; ++k) buf[qbase + k] = td[k];
  __syncthreads();

  if (wave == 0) {
    float sd[NN];
#pragma unroll
    for (int k = 0; k < NN; ++k) sd[k] = BIGF;
    float smax = BIGF;
    for (int w = 0; w < DNW; ++w) {
      for (int c = 0; c < NN; ++c) {
        insert16(sd, smax, buf[(w * 64 + lane) * CSTRIDE + c]);
      }
    }
    float loss = 0.0f;
#pragma unroll
    for (int k = 0; k < NN; ++k) {
      if (sd[k] < RAD2) loss += 1.0f / sqrtf(sd[k] + EPSF);
    }
    for (int off = 32; off > 0; off >>= 1) loss += __shfl_down(loss, off);
    if (lane == 0) block_sums[bid] = loss;
  }
}

// ============ launch ============

extern "C" void kernel_launch(void* const* d_in, const int* in_sizes, int n_in,
                              void* d_out, int out_size, void* d_ws, size_t ws_size,
                              hipStream_t stream) {
  const float* pts = (const float*)d_in[0];
  float* out = (float*)d_out;
  char* ws = (char*)d_ws;

  if (ws_size >= (size_t)WS_NEEDED) {
    int* counts = (int*)(ws + WS_COUNTS);
    int2* rngs = (int2*)(ws + WS_RANGES);
    int* cursor = (int*)(ws + WS_CURSOR);
    float4* sorted = (float4*)(ws + WS_SORTED);
    float* bsums = (float*)(ws + WS_BSUMS);

    zero_kernel<<<(NCELL_TOT + 255) / 256, 256, 0, stream>>>(counts);
    hist_kernel<<<(NTOT + 255) / 256, 256, 0, stream>>>(pts, counts);
    scan_kernel<<<NBATCH, 1024, 0, stream>>>(counts, rngs, cursor);
    scatter_kernel<<<(NTOT + 255) / 256, 256, 0, stream>>>(pts, cursor, sorted);
    search_kernel<<<SNB, STHR, 0, stream>>>(sorted, rngs, bsums);
    finalize_kernel<<<1, 256, 0, stream>>>(bsums, SNB, out);
  } else {
    float* bsums = (float*)ws;
    dense_kernel<<<DNB, DNT, 0, stream>>>(pts, bsums);
    finalize_kernel<<<1, 256, 0, stream>>>(bsums, DNB, out);
  }
}

// Round 11
// 60.980 us; speedup vs baseline: 5.7698x; 1.0702x over previous
//
#include <hip/hip_runtime.h>

#define NPTS 8192
#define NBATCH 4
#define NTOT (NBATCH * NPTS)     // 32768
#define NN 16
#define RAD2 0.25f
#define EPSF 1e-4f
#define BIGF 1e30f

// ---- grid: cell 0.5 over [-4,4), 16 real cells + ghost ring -> 18^3, x fastest ----
#define GC 16
#define GP 18
#define CBS 6144                  // padded per-batch cell stride (>= 18^3 = 5832)
#define NCELL_TOT (NBATCH * CBS)  // 24576

// ---- search: one wave per TWO consecutive (cell-sorted) points ----
#define STHR 256
#define SWV 4
#define PPW 2
#define SNB (NTOT / (SWV * PPW))  // 4096 blocks
#define HCAP 384                  // >= realized max in-RAD2 hits (~330)

// adaptive radius: r0^3 = C / ncand, C = 2.5*(12/pi)*3.375 = 32.23 (target ~40 hits)
#define LOG2C 5.0103f
#define NCLAMP 257                // ncand <= 257 -> r0 clamped to full radius

// ---- ws layout (bytes) ----
#define WS_COUNTS 0
#define WS_RANGES (WS_COUNTS + NCELL_TOT * 4)          // int2
#define WS_CURSOR (WS_RANGES + NCELL_TOT * 8)
#define WS_SORTED (WS_CURSOR + NCELL_TOT * 4)          // float4 (+64 pad)
#define WS_BSUMS  (WS_SORTED + (NTOT + 64) * 16)
#define WS_NEEDED (WS_BSUMS + SNB * 4)

__device__ __forceinline__ int cellc(float v) {
  return min(max((int)floorf((v + 4.0f) * 2.0f), 0), GC - 1);
}

// refined rsqrt: v_rsq + one Newton step (~1-2 ulp; mean over 512K terms absorbs it)
__device__ __forceinline__ float prsqrt(float x) {
  float r = __builtin_amdgcn_rsqf(x);
  r = r * fmaf(-0.5f * x * r, r, 1.5f);
  return r;
}

#define CE(a, b) { const float lo_ = fminf(a, b); const float hi_ = fmaxf(a, b); a = lo_; b = hi_; }

// ============ build ============

__global__ __launch_bounds__(256)
void hist_kernel(const float* __restrict__ pts, int* __restrict__ counts) {
  const int i = blockIdx.x * 256 + threadIdx.x;
  if (i >= NTOT) return;
  const int b = i >> 13;
  const float x = pts[i * 3 + 0], y = pts[i * 3 + 1], z = pts[i * 3 + 2];
  const int c = b * CBS + ((cellc(z) + 1) * GP + (cellc(y) + 1)) * GP + (cellc(x) + 1);
  atomicAdd(&counts[c], 1);
}

// 4 blocks x 1024; thread owns 6 contiguous cells held in regs; 2 barriers total
__global__ __launch_bounds__(1024)
void scan_kernel(const int* __restrict__ counts, int2* __restrict__ ranges,
                 int* __restrict__ cursor) {
  __shared__ int wtot[16];
  __shared__ int woff[16];
  const int b = blockIdx.x;
  const int tid = threadIdx.x;
  const int wid = tid >> 6;
  const int lane = tid & 63;
  const int g0 = b * CBS + tid * 6;

  int v[6];
  int lsum = 0;
#pragma unroll
  for (int k = 0; k < 6; ++k) { v[k] = counts[g0 + k]; lsum += v[k]; }

  // inclusive shfl-scan of per-thread sums within wave
  int x = lsum;
  for (int off = 1; off < 64; off <<= 1) {
    const int t = __shfl_up(x, off, 64);
    if (lane >= off) x += t;
  }
  if (lane == 63) wtot[wid] = x;
  __syncthreads();
  if (wid == 0 && lane < 16) {
    int s = wtot[lane];
    for (int off = 1; off < 16; off <<= 1) {
      const int t = __shfl_up(s, off, 64);
      if (lane >= off) s += t;
    }
    woff[lane] = s - wtot[lane];   // exclusive wave offset
  }
  __syncthreads();

  int run = b * NPTS + woff[wid] + (x - lsum);
#pragma unroll
  for (int k = 0; k < 6; ++k) {
    ranges[g0 + k] = make_int2(run, v[k]);
    cursor[g0 + k] = run;
    run += v[k];
  }
}

__global__ __launch_bounds__(256)
void scatter_kernel(const float* __restrict__ pts, int* __restrict__ cursor,
                    float4* __restrict__ sorted) {
  const int i = blockIdx.x * 256 + threadIdx.x;
  if (i >= NTOT) return;
  const int b = i >> 13;
  const float x = pts[i * 3 + 0], y = pts[i * 3 + 1], z = pts[i * 3 + 2];
  const int c = b * CBS + ((cellc(z) + 1) * GP + (cellc(y) + 1)) * GP + (cellc(x) + 1);
  const int pos = atomicAdd(&cursor[c], 1);
  sorted[pos] = make_float4(x, y, z, fmaf(x, x, fmaf(y, y, z * z)));
}

// ============ search helpers ============

// scan 9 rows [rs,re) for one point; ballot-compact hits (< rr, j != selfp) into hq
__device__ __forceinline__ int scan1(const float4* __restrict__ sorted,
    const int* rs, const int* re, float rr, int selfp,
    float m2x, float m2y, float m2z, float sp, float* __restrict__ hq, int lane) {
  int hcnt = 0;
  const unsigned long long below = (1ull << lane) - 1ull;
#pragma unroll
  for (int m = 0; m < 9; ++m) {
    const int s = rs[m], e = re[m];
    for (int j0 = s; j0 < e; j0 += 64) {
      const int j = j0 + lane;
      float d2 = BIGF;
      if (j < e) {
        const float4 q = sorted[j];
        d2 = fmaf(q.x, m2x, fmaf(q.y, m2y, fmaf(q.z, m2z, q.w + sp)));
      }
      const bool hit = (d2 < rr) && (j != selfp);
      const unsigned long long bal = __ballot(hit);
      const int pos = hcnt + (int)__popcll(bal & below);
      if (hit && pos < HCAP) hq[pos] = d2;
      hcnt += (int)__popcll(bal);
    }
  }
  return hcnt;
}

// scan 9 shared rows once; score both points per candidate
__device__ __forceinline__ void scan2(const float4* __restrict__ sorted,
    const int* rs, const int* re, float rr,
    int pA, float m2xA, float m2yA, float m2zA, float spA,
    int pB, float m2xB, float m2yB, float m2zB, float spB,
    float* __restrict__ hqA, float* __restrict__ hqB, int lane,
    int& hcntA, int& hcntB) {
  int hA = 0, hB = 0;
  const unsigned long long below = (1ull << lane) - 1ull;
#pragma unroll
  for (int m = 0; m < 9; ++m) {
    const int s = rs[m], e = re[m];
    for (int j0 = s; j0 < e; j0 += 64) {
      const int j = j0 + lane;
      float d2A = BIGF, d2B = BIGF;
      if (j < e) {
        const float4 q = sorted[j];
        const float qw = q.w;
        d2A = fmaf(q.x, m2xA, fmaf(q.y, m2yA, fmaf(q.z, m2zA, qw + spA)));
        d2B = fmaf(q.x, m2xB, fmaf(q.y, m2yB, fmaf(q.z, m2zB, qw + spB)));
      }
      const bool hitA = (d2A < rr) && (j != pA);
      const unsigned long long balA = __ballot(hitA);
      const int posA = hA + (int)__popcll(balA & below);
      if (hitA && posA < HCAP) hqA[posA] = d2A;
      hA += (int)__popcll(balA);
      const bool hitB = (d2B < rr) && (j != pB);
      const unsigned long long balB = __ballot(hitB);
      const int posB = hB + (int)__popcll(balB & below);
      if (hitB && posB < HCAP) hqB[posB] = d2B;
      hB += (int)__popcll(balB);
    }
  }
  hcntA = hA;
  hcntB = hB;
}

template<int R>
__device__ __forceinline__ float tourney(const float* __restrict__ hq, int hn, int lane) {
  float v[R];
#pragma unroll
  for (int r = 0; r < R; ++r) {
    const int idx = lane + 64 * r;
    v[r] = (idx < hn) ? hq[idx] : BIGF;
  }
  if constexpr (R == 3) { CE(v[0], v[1]); CE(v[1], v[2]); CE(v[0], v[1]); }
  if constexpr (R == 6) {
    CE(v[0], v[1]); CE(v[2], v[3]); CE(v[4], v[5]);
    CE(v[1], v[2]); CE(v[3], v[4]);
    CE(v[0], v[1]); CE(v[2], v[3]); CE(v[4], v[5]);
    CE(v[1], v[2]); CE(v[3], v[4]);
    CE(v[0], v[1]); CE(v[2], v[3]); CE(v[4], v[5]);
    CE(v[1], v[2]); CE(v[3], v[4]);
  }
  float loss = 0.0f;
#pragma unroll
  for (int r = 0; r < NN; ++r) {
    float g = v[0];
    g = fminf(g, __shfl_xor(g, 1));
    g = fminf(g, __shfl_xor(g, 2));
    g = fminf(g, __shfl_xor(g, 4));
    g = fminf(g, __shfl_xor(g, 8));
    g = fminf(g, __shfl_xor(g, 16));
    g = fminf(g, __shfl_xor(g, 32));
    loss += prsqrt(g + EPSF);    // hn > 64 here => all 16 mins real, < RAD2
    const unsigned long long own = __ballot(v[0] == g);
    const int first = (int)(__ffsll((unsigned long long)own) - 1);
    if (lane == first) {
#pragma unroll
      for (int r2 = 0; r2 < R - 1; ++r2) v[r2] = v[r2 + 1];
      v[R - 1] = BIGF;
    }
  }
  return loss;
}

__device__ __forceinline__ float extract_loss(const float* __restrict__ hq, int hn, int lane) {
  if (hn <= 64) {
    // bitonic sort 64 across lanes, then sum the 16 smallest real hits
    float v = (lane < hn) ? hq[lane] : BIGF;
#pragma unroll
    for (int k = 2; k <= 64; k <<= 1) {
#pragma unroll
      for (int j = k >> 1; j > 0; j >>= 1) {
        const float o = __shfl_xor(v, j, 64);
        const bool keepmin = (((lane & j) == 0) != ((lane & k) != 0));
        v = keepmin ? fminf(v, o) : fmaxf(v, o);
      }
    }
    float l = (lane < NN && v < RAD2) ? prsqrt(v + EPSF) : 0.0f;
    l += __shfl_xor(l, 1);
    l += __shfl_xor(l, 2);
    l += __shfl_xor(l, 4);
    l += __shfl_xor(l, 8);
    l += __shfl_xor(l, 16);
    l += __shfl_xor(l, 32);
    return l;
  } else if (hn <= 192) {
    return tourney<3>(hq, hn, lane);
  }
  return tourney<6>(hq, hn, lane);
}

// ============ search: wave = 2 consecutive cell-sorted points ============
// Pair->wave assignment is STRIDED (pair = wv*SNB + bid) so each block mixes
// 4 pairs from widely-separated strata of the sorted order -> balanced blocks.

__global__ __launch_bounds__(STHR)
void search_kernel(const float4* __restrict__ sorted, const int2* __restrict__ rngs,
                   float* __restrict__ bsums) {
  __shared__ float hbuf[SWV][2][HCAP];   // 12.3 KB
  __shared__ float wloss[SWV];

  const int tid = threadIdx.x;
  const int wv = tid >> 6;
  const int lane = tid & 63;
  const int pair = wv * SNB + blockIdx.x;      // strided for load balance
  const int p0 = pair * 2;
  const int p1 = p0 + 1;
  const int bb = p0 >> 13;               // pairs never straddle batches (8192 even)

  const float4 ptA = sorted[p0];
  const float4 ptB = sorted[p1];
  const float m2xA = -2.0f * ptA.x, m2yA = -2.0f * ptA.y, m2zA = -2.0f * ptA.z;
  const float spA = ptA.w;
  const float m2xB = -2.0f * ptB.x, m2yB = -2.0f * ptB.y, m2zB = -2.0f * ptB.z;
  const float spB = ptB.w;

  const int rbA = __builtin_amdgcn_readfirstlane(
      bb * CBS + ((cellc(ptA.z) + 1) * GP + (cellc(ptA.y) + 1)) * GP);
  const int rbB = __builtin_amdgcn_readfirstlane(
      bb * CBS + ((cellc(ptB.z) + 1) * GP + (cellc(ptB.y) + 1)) * GP);
  const int xA = __builtin_amdgcn_readfirstlane(cellc(ptA.x));
  const int xB = __builtin_amdgcn_readfirstlane(cellc(ptB.x));

  const int rowoff[9] = {
    (-1 * GP - 1) * GP, (-1 * GP + 0) * GP, (-1 * GP + 1) * GP,
    ( 0 * GP - 1) * GP, ( 0 * GP + 0) * GP, ( 0 * GP + 1) * GP,
    ( 1 * GP - 1) * GP, ( 1 * GP + 0) * GP, ( 1 * GP + 1) * GP };

  float* hqA = hbuf[wv][0];
  float* hqB = hbuf[wv][1];
  int hnA, hnB;

  if (rbA == rbB) {
    // shared/union path (~98% of pairs): ghost x-window [min, max+2]
    const int lo = min(xA, xB);
    const int hi = max(xA, xB) + 2;
    int rs[9], re[9], ncand = 0;
#pragma unroll
    for (int m = 0; m < 9; ++m) {
      const int base = rbA + rowoff[m];
      const int2 a = rngs[base + lo];
      const int2 b = rngs[base + hi];
      rs[m] = a.x;
      re[m] = b.x + b.y;
      ncand += re[m] - rs[m];
    }
    const bool clamped = (ncand <= NCLAMP);
    float r0sq = RAD2;
    if (!clamped) r0sq = exp2f((LOG2C - log2f((float)ncand)) * (2.0f / 3.0f));

    int hA, hB;
    scan2(sorted, rs, re, r0sq, p0, m2xA, m2yA, m2zA, spA,
          p1, m2xB, m2yB, m2zB, spB, hqA, hqB, lane, hA, hB);
    hnA = min(hA, HCAP);
    hnB = min(hB, HCAP);
    // rare rescans at full radius (union rows are a safe superset for each point)
    if (hnA < NN && !clamped)
      hnA = min(scan1(sorted, rs, re, RAD2, p0, m2xA, m2yA, m2zA, spA, hqA, lane), HCAP);
    if (hnB < NN && !clamped)
      hnB = min(scan1(sorted, rs, re, RAD2, p1, m2xB, m2yB, m2zB, spB, hqB, lane), HCAP);
  } else {
    // row-straddle (~1-2%): two independent solo scans
    int rsA[9], reA[9], ncA = 0, rsB[9], reB[9], ncB = 0;
#pragma unroll
    for (int m = 0; m < 9; ++m) {
      const int baseA = rbA + rowoff[m];
      const int2 a0 = rngs[baseA + xA];
      const int2 a1 = rngs[baseA + xA + 2];
      rsA[m] = a0.x; reA[m] = a1.x + a1.y; ncA += reA[m] - rsA[m];
      const int baseB = rbB + rowoff[m];
      const int2 b0 = rngs[baseB + xB];
      const int2 b1 = rngs[baseB + xB + 2];
      rsB[m] = b0.x; reB[m] = b1.x + b1.y; ncB += reB[m] - rsB[m];
    }
    const bool clA = (ncA <= NCLAMP);
    const bool clB = (ncB <= NCLAMP);
    float rA = RAD2, rB = RAD2;
    if (!clA) rA = exp2f((LOG2C - log2f((float)ncA)) * (2.0f / 3.0f));
    if (!clB) rB = exp2f((LOG2C - log2f((float)ncB)) * (2.0f / 3.0f));
    hnA = min(scan1(sorted, rsA, reA, rA, p0, m2xA, m2yA, m2zA, spA, hqA, lane), HCAP);
    if (hnA < NN && !clA)
      hnA = min(scan1(sorted, rsA, reA, RAD2, p0, m2xA, m2yA, m2zA, spA, hqA, lane), HCAP);
    hnB = min(scan1(sorted, rsB, reB, rB, p1, m2xB, m2yB, m2zB, spB, hqB, lane), HCAP);
    if (hnB < NN && !clB)
      hnB = min(scan1(sorted, rsB, reB, RAD2, p1, m2xB, m2yB, m2zB, spB, hqB, lane), HCAP);
  }

  const float lossA = extract_loss(hqA, hnA, lane);
  const float lossB = extract_loss(hqB, hnB, lane);

  if (lane == 0) wloss[wv] = lossA + lossB;
  __syncthreads();
  if (tid == 0) {
    float s = 0.0f;
#pragma unroll
    for (int w = 0; w < SWV; ++w) s += wloss[w];
    bsums[blockIdx.x] = s;
  }
}

__global__ __launch_bounds__(256)
void finalize_kernel(const float* __restrict__ block_sums, int nblocks,
                     float* __restrict__ out) {
  __shared__ float s[256];
  float v = 0.0f;
  for (int idx = threadIdx.x; idx < nblocks; idx += 256) v += block_sums[idx];
  s[threadIdx.x] = v;
  __syncthreads();
  for (int off = 128; off > 0; off >>= 1) {
    if (threadIdx.x < off) s[threadIdx.x] += s[threadIdx.x + off];
    __syncthreads();
  }
  if (threadIdx.x == 0) out[0] = s[0] / (float)(NBATCH * NPTS * NN);
}

// ============ dense fallback (if ws too small) ============

#define DTILE 1024
#define DNT 512
#define DNW 8
#define DNB (NTOT / 64)
#define CSTRIDE 17
#define QTRIG 13

__device__ __forceinline__ void insert16(float (&td)[NN], float& thrmax, float v) {
  if (v < thrmax) {
    bool done = false;
#pragma unroll
    for (int k = 0; k < NN; ++k) {
      const bool hit = (!done) && (td[k] == thrmax);
      if (hit) td[k] = v;
      done = done || hit;
    }
    thrmax = td[0];
#pragma unroll
    for (int k = 1; k < NN; ++k) thrmax = fmaxf(thrmax, td[k]);
  }
}

__device__ __forceinline__ void drain_queue(float* buf, int qbase, int& cnt,
                                            float (&td)[NN], float& thrmax) {
#pragma unroll
  for (int c = 0; c < 16; ++c) {
    const float v = (c < cnt) ? buf[qbase + c] : BIGF;
    insert16(td, thrmax, v);
  }
  cnt = 0;
}

__global__ __launch_bounds__(DNT)
void dense_kernel(const float* __restrict__ pts, float* __restrict__ block_sums) {
  __shared__ float4 tile[DTILE];
  __shared__ float buf[DNT * CSTRIDE];

  const int tid = threadIdx.x;
  const int wave = tid >> 6;
  const int lane = tid & 63;
  const int bid = blockIdx.x;
  const int b = bid / (NPTS / 64);
  const int base = (bid % (NPTS / 64)) * 64;
  const float* __restrict__ bp = pts + (size_t)b * NPTS * 3;

  const int i = base + lane;
  const float xi = bp[i * 3 + 0];
  const float yi = bp[i * 3 + 1];
  const float zi = bp[i * 3 + 2];

  float td[NN];
#pragma unroll
  for (int k = 0; k < NN; ++k) td[k] = BIGF;
  float thrmax = BIGF;
  int cnt = 0;
  const int qbase = tid * CSTRIDE;

  for (int tb = 0; tb < NPTS; tb += DTILE) {
    for (int pp = tid; pp < DTILE; pp += DNT) {
      const float* sp = bp + (size_t)(tb + pp) * 3;
      tile[pp] = make_float4(sp[0], sp[1], sp[2], 0.0f);
    }
    __syncthreads();
    const int jb = wave * (DTILE / DNW);
    for (int jj = 0; jj < DTILE / DNW; ++jj) {
      const float4 q = tile[jb + jj];
      const float ddx = q.x - xi, ddy = q.y - yi, ddz = q.z - zi;
      const float d2 = fmaf(ddx, ddx, fmaf(ddy, ddy, ddz * ddz));
      if (d2 < RAD2 && d2 != 0.0f) {
        buf[qbase + cnt] = d2;
        ++cnt;
      }
      if (__any(cnt >= QTRIG)) drain_queue(buf, qbase, cnt, td, thrmax);
    }
    __syncthreads();
  }
  drain_queue(buf, qbase, cnt, td, thrmax);
#pragma unroll
  for (int k = 0; k < NN; ++k) buf[qbase + k] = td[k];
  __syncthreads();

  if (wave == 0) {
    float sd[NN];
#pragma unroll
    for (int k = 0; k < NN; ++k) sd[k] = BIGF;
    float smax = BIGF;
    for (int w = 0; w < DNW; ++w) {
      for (int c = 0; c < NN; ++c) {
        insert16(sd, smax, buf[(w * 64 + lane) * CSTRIDE + c]);
      }
    }
    float loss = 0.0f;
#pragma unroll
    for (int k = 0; k < NN; ++k) {
      if (sd[k] < RAD2) loss += 1.0f / sqrtf(sd[k] + EPSF);
    }
    for (int off = 32; off > 0; off >>= 1) loss += __shfl_down(loss, off);
    if (lane == 0) block_sums[bid] = loss;
  }
}

// ============ launch ============

extern "C" void kernel_launch(void* const* d_in, const int* in_sizes, int n_in,
                              void* d_out, int out_size, void* d_ws, size_t ws_size,
                              hipStream_t stream) {
  const float* pts = (const float*)d_in[0];
  float* out = (float*)d_out;
  char* ws = (char*)d_ws;

  if (ws_size >= (size_t)WS_NEEDED) {
    int* counts = (int*)(ws + WS_COUNTS);
    int2* rngs = (int2*)(ws + WS_RANGES);
    int* cursor = (int*)(ws + WS_CURSOR);
    float4* sorted = (float4*)(ws + WS_SORTED);
    float* bsums = (float*)(ws + WS_BSUMS);

    hipMemsetAsync(counts, 0, NCELL_TOT * 4, stream);
    hist_kernel<<<(NTOT + 255) / 256, 256, 0, stream>>>(pts, counts);
    scan_kernel<<<NBATCH, 1024, 0, stream>>>(counts, rngs, cursor);
    scatter_kernel<<<(NTOT + 255) / 256, 256, 0, stream>>>(pts, cursor, sorted);
    search_kernel<<<SNB, STHR, 0, stream>>>(sorted, rngs, bsums);
    finalize_kernel<<<1, 256, 0, stream>>>(bsums, SNB, out);
  } else {
    float* bsums = (float*)ws;
    dense_kernel<<<DNB, DNT, 0, stream>>>(pts, bsums);
    finalize_kernel<<<1, 256, 0, stream>>>(bsums, DNB, out);
  }
}